// Round 2
// baseline (69219.489 us; speedup 1.0000x reference)
//
#include <hip/hip_runtime.h>

// Problem constants
#define B_   128
#define T_   128
#define E_   1024
#define H_   1024
#define A_   64
#define NH_  8
#define G_   3072      // 3*H
#define QK_  512       // NH*A
#define SCALE_ 0.125f

// ---------------------------------------------------------------------------
// JAX Threefry-2x32-20 (bit-exact) + XLA f32 erfinv path
// ---------------------------------------------------------------------------
__device__ __forceinline__ unsigned rotl32(unsigned x, int r) {
  return (x << r) | (x >> (32 - r));
}

__device__ __forceinline__ void tf2x32(unsigned k0, unsigned k1,
                                       unsigned x0, unsigned x1,
                                       unsigned& o0, unsigned& o1) {
  unsigned k2 = k0 ^ k1 ^ 0x1BD11BDAu;
  x0 += k0; x1 += k1;
  x0 += x1; x1 = rotl32(x1, 13); x1 ^= x0;
  x0 += x1; x1 = rotl32(x1, 15); x1 ^= x0;
  x0 += x1; x1 = rotl32(x1, 26); x1 ^= x0;
  x0 += x1; x1 = rotl32(x1,  6); x1 ^= x0;
  x0 += k1; x1 += k2 + 1u;
  x0 += x1; x1 = rotl32(x1, 17); x1 ^= x0;
  x0 += x1; x1 = rotl32(x1, 29); x1 ^= x0;
  x0 += x1; x1 = rotl32(x1, 16); x1 ^= x0;
  x0 += x1; x1 = rotl32(x1, 24); x1 ^= x0;
  x0 += k2; x1 += k0 + 2u;
  x0 += x1; x1 = rotl32(x1, 13); x1 ^= x0;
  x0 += x1; x1 = rotl32(x1, 15); x1 ^= x0;
  x0 += x1; x1 = rotl32(x1, 26); x1 ^= x0;
  x0 += x1; x1 = rotl32(x1,  6); x1 ^= x0;
  x0 += k0; x1 += k1 + 3u;
  x0 += x1; x1 = rotl32(x1, 17); x1 ^= x0;
  x0 += x1; x1 = rotl32(x1, 29); x1 ^= x0;
  x0 += x1; x1 = rotl32(x1, 16); x1 ^= x0;
  x0 += x1; x1 = rotl32(x1, 24); x1 ^= x0;
  x0 += k1; x1 += k2 + 4u;
  x0 += x1; x1 = rotl32(x1, 13); x1 ^= x0;
  x0 += x1; x1 = rotl32(x1, 15); x1 ^= x0;
  x0 += x1; x1 = rotl32(x1, 26); x1 ^= x0;
  x0 += x1; x1 = rotl32(x1,  6); x1 ^= x0;
  x0 += k2; x1 += k0 + 5u;
  o0 = x0; o1 = x1;
}

__device__ __forceinline__ float bits_to_normal(unsigned bits) {
  float uf = __uint_as_float((bits >> 9) | 0x3F800000u) - 1.0f;
  const float LO = -0.99999994f;
  float u = fmaxf(LO, uf * 2.0f + LO);
  float w = -log1pf(-u * u);
  float p;
  if (w < 5.0f) {
    w -= 2.5f;
    p = 2.81022636e-08f;
    p = fmaf(p, w, 3.43273939e-07f);
    p = fmaf(p, w, -3.5233877e-06f);
    p = fmaf(p, w, -4.39150654e-06f);
    p = fmaf(p, w, 0.00021858087f);
    p = fmaf(p, w, -0.00125372503f);
    p = fmaf(p, w, -0.00417768164f);
    p = fmaf(p, w, 0.246640727f);
    p = fmaf(p, w, 1.50140941f);
  } else {
    w = sqrtf(w) - 3.0f;
    p = -0.000200214257f;
    p = fmaf(p, w, 0.000100950558f);
    p = fmaf(p, w, 0.00134934322f);
    p = fmaf(p, w, -0.00367342844f);
    p = fmaf(p, w, 0.00573950773f);
    p = fmaf(p, w, -0.0076224613f);
    p = fmaf(p, w, 0.00943887047f);
    p = fmaf(p, w, 1.00167406f);
    p = fmaf(p, w, 2.83297682f);
  }
  return 1.41421356f * p * u;
}

__device__ __forceinline__ float sigmoidf_(float x) {
  return 1.0f / (1.0f + expf(-x));
}

// Dtype-dispatched element load (flag: 1 = buffer is bf16, 0 = f32)
__device__ __forceinline__ float ld_elem(const void* p, long i, int isb) {
  if (isb) {
    unsigned short u = ((const unsigned short*)p)[i];
    return __uint_as_float(((unsigned)u) << 16);
  }
  return ((const float*)p)[i];
}

// ---------------------------------------------------------------------------
// Sniff input dtype from encs: bf16-packed words carry an exponent signature
// in bits 8..15 (the low element's sign+exp[7:1]); f32 mantissa bits there
// are ~uniform. >50% hits over 4096 words => bf16.
// ---------------------------------------------------------------------------
__global__ __launch_bounds__(256) void sniff_kernel(const void* encs, int* flag) {
  __shared__ int cnt;
  if (threadIdx.x == 0) cnt = 0;
  __syncthreads();
  const unsigned* w = (const unsigned*)encs;
  int c = 0;
  for (int i = threadIdx.x; i < 4096; i += 256) {
    unsigned e7 = (w[i] >> 8) & 0x7F;
    if (e7 >= 0x3B && e7 <= 0x41) c++;
  }
  atomicAdd(&cnt, c);
  __syncthreads();
  if (threadIdx.x == 0) flag[0] = (cnt > 2048) ? 1 : 0;
}

// Generic converter: dst[i] = (float)src[i] per flag
__global__ __launch_bounds__(256) void conv_kernel(const void* src, float* dst,
                                                   long n, const int* flag) {
  long i = (long)blockIdx.x * 256 + threadIdx.x;
  int isb = flag[0];
  if (i < n) dst[i] = ld_elem(src, i, isb);
}

// ---------------------------------------------------------------------------
// Weight transposes (dtype-dispatched) + zero h/context
// ---------------------------------------------------------------------------
__global__ __launch_bounds__(256) void trans_kernel(
    const void* W_ih, const void* W_hh, const void* W_k,
    float* __restrict__ WT_enc, float* __restrict__ WT_ctx,
    float* __restrict__ WT_hh, float* __restrict__ WkT,
    float* __restrict__ hA, float* __restrict__ hB, float* __restrict__ ctxv,
    const int* flag)
{
  long idx = (long)blockIdx.x * 256 + threadIdx.x;
  int which = blockIdx.y;
  int isb = flag[0];
  if (which == 0) {
    if (idx < (long)E_ * G_) {
      int e = (int)(idx & 1023); long g = idx >> 10;
      WT_enc[(long)e * G_ + g] = ld_elem(W_ih, g * 2048 + e, isb);
    }
  } else if (which == 1) {
    if (idx < (long)E_ * G_) {
      int e = (int)(idx & 1023); long g = idx >> 10;
      WT_ctx[(long)e * G_ + g] = ld_elem(W_ih, g * 2048 + 1024 + e, isb);
    }
  } else if (which == 2) {
    if (idx < (long)H_ * G_) {
      int e = (int)(idx & 1023); long g = idx >> 10;
      WT_hh[(long)e * G_ + g] = ld_elem(W_hh, g * 1024 + e, isb);
    }
  } else {
    if (idx < (long)QK_ * E_) {
      int e = (int)(idx & 1023); long qk = idx >> 10;
      WkT[qk * 1024 + e] = ld_elem(W_k, e * 512 + qk, isb);
    }
    if (idx < B_ * H_) { hA[idx] = 0.f; hB[idx] = 0.f; ctxv[idx] = 0.f; }
  }
}

// ---------------------------------------------------------------------------
// Generic 64x64 tiled matmul: C[m][n] = sum_k A[m][k]*Bm[k][n] (+bias)(epi)
// ---------------------------------------------------------------------------
__global__ __launch_bounds__(256) void mm64(
    const float* __restrict__ A, long lda, long zA,
    const float* __restrict__ Bm, long ldb, long zB,
    const float* __restrict__ bias_row, long zBias,
    const float* __restrict__ bias2d, long ld2d,
    float* __restrict__ C, long ldc, long zC,
    int K, int mode)
{
  int z = blockIdx.z;
  A += (long)z * zA; Bm += (long)z * zB; C += (long)z * zC;
  if (bias_row) bias_row += (long)z * zBias;
  long n0 = (long)blockIdx.x * 64;
  long m0 = (long)blockIdx.y * 64;
  __shared__ float As[16][68];
  __shared__ float Bs[16][68];
  int tid = threadIdx.x;
  int tx = tid & 15, ty = tid >> 4;
  int ar = tid >> 2, ac = tid & 3;
  int br = tid >> 4, bc = tid & 15;
  float acc[4][4];
  #pragma unroll
  for (int i = 0; i < 4; ++i)
    #pragma unroll
    for (int j = 0; j < 4; ++j) acc[i][j] = 0.f;

  for (int k0 = 0; k0 < K; k0 += 16) {
    float4 a4 = *(const float4*)(A + (m0 + ar) * lda + k0 + 4 * ac);
    float4 b4 = *(const float4*)(Bm + (long)(k0 + br) * ldb + n0 + 4 * bc);
    __syncthreads();
    As[4 * ac + 0][ar] = a4.x;
    As[4 * ac + 1][ar] = a4.y;
    As[4 * ac + 2][ar] = a4.z;
    As[4 * ac + 3][ar] = a4.w;
    *(float4*)(&Bs[br][4 * bc]) = b4;
    __syncthreads();
    #pragma unroll
    for (int kk = 0; kk < 16; ++kk) {
      float4 av = *(const float4*)(&As[kk][4 * ty]);
      float4 bv = *(const float4*)(&Bs[kk][4 * tx]);
      float am[4] = {av.x, av.y, av.z, av.w};
      float bn[4] = {bv.x, bv.y, bv.z, bv.w};
      #pragma unroll
      for (int im = 0; im < 4; ++im)
        #pragma unroll
        for (int in2 = 0; in2 < 4; ++in2)
          acc[im][in2] = fmaf(am[im], bn[in2], acc[im][in2]);
    }
  }

  #pragma unroll
  for (int im = 0; im < 4; ++im) {
    long m = m0 + ty * 4 + im;
    float4 v;
    float* vp = (float*)&v;
    #pragma unroll
    for (int in2 = 0; in2 < 4; ++in2) {
      long n = n0 + tx * 4 + in2;
      float val = acc[im][in2];
      if (bias_row) val += bias_row[n];
      if (bias2d)   val += bias2d[m * ld2d + n];
      if (mode == 1) val = fmaxf(val, 0.0f) + log1pf(expf(-fabsf(val)));
      vp[in2] = val;
    }
    *(float4*)(C + m * ldc + n0 + tx * 4) = v;
  }
}

// ---------------------------------------------------------------------------
// GRU gate combine
// ---------------------------------------------------------------------------
__global__ __launch_bounds__(256) void gru_combine(
    const float* __restrict__ gihat, const float* __restrict__ ghhat,
    const float* __restrict__ h_old, float* __restrict__ h_new)
{
  int idx = blockIdx.x * 256 + threadIdx.x;  // < B*H
  int b = idx >> 10, j = idx & 1023;
  const float* gi = gihat + (long)b * G_;
  const float* gh = ghhat + (long)b * G_;
  float ir = gi[j], iz = gi[1024 + j], inn = gi[2048 + j];
  float hr = gh[j], hz = gh[1024 + j], hn  = gh[2048 + j];
  float r = sigmoidf_(ir + hr);
  float z = sigmoidf_(iz + hz);
  float n = tanhf(inn + r * hn);
  float ho = h_old[idx];
  h_new[idx] = (1.0f - z) * n + z * ho;
}

// ---------------------------------------------------------------------------
// s[b,t,e] = mus + eps*sigs, partitionable threefry:
//   per-element 64-bit counter (hi=0, lo=flat idx), bits = out0 ^ out1
// grid: (E/256, step+1, 128)
// ---------------------------------------------------------------------------
__global__ __launch_bounds__(256) void gen_s(
    const float* __restrict__ mus, const float* __restrict__ sigs,
    float* __restrict__ s, int step)
{
  int e = blockIdx.x * 256 + threadIdx.x;
  int t = blockIdx.y;
  int b = blockIdx.z;  // 0..127
  unsigned sk0, sk1;
  tf2x32(0u, 1234u, 0u, (unsigned)step, sk0, sk1);   // fold_in(key(1234), step)
  unsigned f = (unsigned)b * (T_ * E_) + (unsigned)t * E_ + (unsigned)e;
  unsigned o0, o1;
  tf2x32(sk0, sk1, 0u, f, o0, o1);
  unsigned bits = o0 ^ o1;
  long i0 = (long)b * T_ * E_ + (long)t * E_ + e;
  s[i0] = fmaf(bits_to_normal(bits), sigs[i0], mus[i0]);
}

// ---------------------------------------------------------------------------
// t[b,h,e] = sum_a q[b,h*64+a] * WkT[h*64+a][e];  qb[b,h] = sum_a q*b_k
// ---------------------------------------------------------------------------
__global__ __launch_bounds__(256) void t_kernel(
    const float* __restrict__ q, const float* __restrict__ WkT,
    const float* __restrict__ b_k, float* __restrict__ tmat,
    float* __restrict__ qb)
{
  int e = blockIdx.x * 256 + threadIdx.x;
  int h = blockIdx.y;
  int b0 = blockIdx.z * 8;
  __shared__ float q_l[8][64];
  int tid = threadIdx.x;
  for (int idx2 = tid; idx2 < 512; idx2 += 256) {
    int bb = idx2 >> 6, a = idx2 & 63;
    q_l[bb][a] = q[(long)(b0 + bb) * QK_ + h * 64 + a];
  }
  __syncthreads();
  float acc[8];
  #pragma unroll
  for (int bb = 0; bb < 8; ++bb) acc[bb] = 0.f;
  for (int a = 0; a < 64; ++a) {
    float wv = WkT[(long)(h * 64 + a) * E_ + e];
    #pragma unroll
    for (int bb = 0; bb < 8; ++bb) acc[bb] = fmaf(q_l[bb][a], wv, acc[bb]);
  }
  #pragma unroll
  for (int bb = 0; bb < 8; ++bb)
    tmat[((long)(b0 + bb) * NH_ + h) * E_ + e] = acc[bb];
  if (blockIdx.x == 0 && tid < 8) {
    int bb = tid;
    float sm = 0.f;
    for (int a = 0; a < 64; ++a) sm += q_l[bb][a] * b_k[h * 64 + a];
    qb[(b0 + bb) * NH_ + h] = sm;
  }
}

// ---------------------------------------------------------------------------
// Fused scores -> softmax -> ctxE.  One block per b (256 threads).
// ---------------------------------------------------------------------------
__global__ __launch_bounds__(256) void attn_kernel(
    const float* __restrict__ s, const float* __restrict__ tmat,
    const float* __restrict__ qb, float* __restrict__ ctxE, int step)
{
  int b = blockIdx.x;
  int tid = threadIdx.x;
  __shared__ float t_lds[NH_ * E_];   // 32 KB
  __shared__ float s_lds[E_];         // 4 KB
  __shared__ float sc[NH_ * T_];      // 4 KB
  __shared__ float wj_lds[NH_ * T_];  // 4 KB
  __shared__ float qb_l[NH_];

  const float4* tg = (const float4*)(tmat + (long)b * (NH_ * E_));
  float4* tl = (float4*)t_lds;
  for (int k = tid; k < (NH_ * E_) / 4; k += 256) tl[k] = tg[k];
  if (tid < NH_) qb_l[tid] = qb[b * NH_ + tid];

  int h = tid >> 5, e0 = tid & 31;
  float acc[32];
  #pragma unroll
  for (int k = 0; k < 32; ++k) acc[k] = 0.f;
  __syncthreads();

  for (int j = 0; j <= step; ++j) {
    __syncthreads();
    ((float4*)s_lds)[tid] = ((const float4*)(s + ((long)b * T_ + j) * E_))[tid];
    __syncthreads();
    float p = 0.f;
    #pragma unroll
    for (int k = 0; k < 32; ++k)
      p = fmaf(s_lds[e0 + 32 * k], t_lds[h * E_ + e0 + 32 * k], p);
    for (int off = 16; off; off >>= 1) p += __shfl_xor(p, off, 32);
    if (e0 == 0) sc[h * T_ + j] = (p + qb_l[h]) * SCALE_;
  }
  __syncthreads();

  {
    float m = -3.0e38f;
    for (int j = e0; j <= step; j += 32) m = fmaxf(m, sc[h * T_ + j]);
    for (int off = 16; off; off >>= 1) m = fmaxf(m, __shfl_xor(m, off, 32));
    float d = 0.f;
    for (int j = e0; j <= step; j += 32) {
      float pe = expf(sc[h * T_ + j] - m);
      wj_lds[h * T_ + j] = pe;
      d += pe;
    }
    for (int off = 16; off; off >>= 1) d += __shfl_xor(d, off, 32);
    for (int j = e0; j <= step; j += 32) wj_lds[h * T_ + j] = wj_lds[h * T_ + j] / d;
  }
  __syncthreads();

  for (int j = 0; j <= step; ++j) {
    __syncthreads();
    ((float4*)s_lds)[tid] = ((const float4*)(s + ((long)b * T_ + j) * E_))[tid];
    __syncthreads();
    float wj = wj_lds[h * T_ + j];
    #pragma unroll
    for (int k = 0; k < 32; ++k) acc[k] = fmaf(wj, s_lds[e0 + 32 * k], acc[k]);
  }
  float* cg = ctxE + (long)b * (NH_ * E_) + (long)h * E_;
  #pragma unroll
  for (int k = 0; k < 32; ++k) cg[e0 + 32 * k] = acc[k];
}

// ---------------------------------------------------------------------------
// Host side
// ---------------------------------------------------------------------------
extern "C" void kernel_launch(void* const* d_in, const int* in_sizes, int n_in,
                              void* d_out, int out_size, void* d_ws, size_t ws_size,
                              hipStream_t stream) {
  (void)in_sizes; (void)n_in; (void)out_size; (void)ws_size;
  const void* encs  = d_in[0];
  const void* W_ih  = d_in[1];
  const void* W_hh  = d_in[2];
  const void* b_ih  = d_in[3];
  const void* b_hh  = d_in[4];
  const void* W_mu  = d_in[5];
  const void* b_mu  = d_in[6];
  const void* W_sig = d_in[7];
  const void* b_sig = d_in[8];
  const void* W_q   = d_in[9];
  const void* b_q   = d_in[10];
  const void* W_k   = d_in[11];
  const void* b_k   = d_in[12];
  const void* W_v   = d_in[13];
  const void* b_v   = d_in[14];
  const void* W_o   = d_in[15];
  const void* b_o   = d_in[16];

  float* s = (float*)d_out;   // s buffer doubles as the final output
  float* w = (float*)d_ws;

  // workspace layout (floats)
  int*   flag   = (int*)w;                         // [0]
  float* p      = w + 1024;
  const size_t SZ_WT = (size_t)E_ * G_;
  float* WT_enc = p;              p += SZ_WT;
  float* WT_ctx = p;              p += SZ_WT;
  float* WT_hh  = p;              p += SZ_WT;
  float* WkT    = p;              p += (size_t)QK_ * E_;
  // f32 input copies
  float* encsF  = p;              p += (size_t)B_ * E_;
  float* bihF   = p;              p += G_;
  float* bhhF   = p;              p += G_;
  float* WmuF   = p;              p += (size_t)H_ * E_;
  float* bmuF   = p;              p += 1024;
  float* WsigF  = p;              p += (size_t)H_ * E_;
  float* bsigF  = p;              p += 1024;
  float* WqF    = p;              p += (size_t)E_ * QK_;
  float* bqF    = p;              p += 1024;
  float* bkF    = p;              p += 1024;
  float* WvF    = p;              p += (size_t)E_ * QK_;
  float* bvF    = p;              p += 1024;
  float* WoF    = p;              p += (size_t)QK_ * E_;
  float* boF    = p;              p += 1024;
  // loop buffers
  float* gienc  = p;              p += (size_t)B_ * G_;
  float* hA     = p;              p += (size_t)B_ * H_;
  float* hB     = p;              p += (size_t)B_ * H_;
  float* ctxv   = p;              p += (size_t)B_ * E_;
  float* gihat  = p;              p += (size_t)B_ * G_;
  float* ghhat  = p;              p += (size_t)B_ * G_;
  float* qws    = p;              p += (size_t)B_ * QK_;
  float* qbws   = p;              p += 1024;
  float* tmat   = p;              p += (size_t)B_ * NH_ * E_;
  float* ctxE   = p;              p += (size_t)B_ * NH_ * E_;
  float* ctxh   = p;              p += (size_t)B_ * QK_;
  float* mus    = p;              p += (size_t)B_ * T_ * E_;
  float* sigs   = p;              p += (size_t)B_ * T_ * E_;
  // total ~51.1M floats ~ 205 MB

  // 0) dtype sniff
  sniff_kernel<<<1, 256, 0, stream>>>(encs, flag);

  // 1) convert inputs used directly as f32
  auto conv = [&](const void* src, float* dst, long n) {
    conv_kernel<<<dim3((unsigned)((n + 255) / 256)), 256, 0, stream>>>(src, dst, n, flag);
  };
  conv(encs,  encsF, (long)B_ * E_);
  conv(b_ih,  bihF,  G_);
  conv(b_hh,  bhhF,  G_);
  conv(W_mu,  WmuF,  (long)H_ * E_);
  conv(b_mu,  bmuF,  1024);
  conv(W_sig, WsigF, (long)H_ * E_);
  conv(b_sig, bsigF, 1024);
  conv(W_q,   WqF,   (long)E_ * QK_);
  conv(b_q,   bqF,   512);
  conv(b_k,   bkF,   512);
  conv(W_v,   WvF,   (long)E_ * QK_);
  conv(b_v,   bvF,   512);
  conv(W_o,   WoF,   (long)QK_ * E_);
  conv(b_o,   boF,   1024);

  // 2) transposes + zero init
  trans_kernel<<<dim3(12288, 4), 256, 0, stream>>>(
      W_ih, W_hh, W_k, WT_enc, WT_ctx, WT_hh, WkT, hA, hB, ctxv, flag);

  // 3) gi_enc = encs @ WT_enc + b_ih
  mm64<<<dim3(G_ / 64, B_ / 64, 1), 256, 0, stream>>>(
      encsF, E_, 0, WT_enc, G_, 0, bihF, 0, nullptr, 0, gienc, G_, 0, E_, 0);

  float* h_in = hA;
  float* h_out = hB;
  for (int i = 0; i < T_; ++i) {
    // M1: gihat = context @ WT_ctx + gi_enc (2D add)
    mm64<<<dim3(G_ / 64, B_ / 64, 1), 256, 0, stream>>>(
        ctxv, E_, 0, WT_ctx, G_, 0, nullptr, 0, gienc, G_, gihat, G_, 0, E_, 0);
    // M2: ghhat = h @ WT_hh + b_hh
    mm64<<<dim3(G_ / 64, B_ / 64, 1), 256, 0, stream>>>(
        h_in, H_, 0, WT_hh, G_, 0, bhhF, 0, nullptr, 0, ghhat, G_, 0, H_, 0);
    // M3: GRU combine
    gru_combine<<<dim3(B_ * H_ / 256), 256, 0, stream>>>(gihat, ghhat, h_in, h_out);
    // M4a: mu -> mus[:, i, :]
    mm64<<<dim3(E_ / 64, B_ / 64, 1), 256, 0, stream>>>(
        h_out, H_, 0, WmuF, E_, 0, bmuF, 0, nullptr, 0,
        mus + (long)i * E_, (long)T_ * E_, 0, H_, 0);
    // M4b: sig = softplus(...) -> sigs[:, i, :]
    mm64<<<dim3(E_ / 64, B_ / 64, 1), 256, 0, stream>>>(
        h_out, H_, 0, WsigF, E_, 0, bsigF, 0, nullptr, 0,
        sigs + (long)i * E_, (long)T_ * E_, 0, H_, 1);
    // M5: s rows 0..i (partitionable threefry noise)
    gen_s<<<dim3(E_ / 256, i + 1, B_), 256, 0, stream>>>(mus, sigs, s, i);
    // M6: q = s[:, i, :] @ W_q + b_q
    mm64<<<dim3(QK_ / 64, B_ / 64, 1), 256, 0, stream>>>(
        s + (long)i * E_, (long)T_ * E_, 0, WqF, QK_, 0, bqF, 0, nullptr, 0,
        qws, QK_, 0, E_, 0);
    // M7: t[b,h,e], qb[b,h]
    t_kernel<<<dim3(E_ / 256, NH_, B_ / 8), 256, 0, stream>>>(
        qws, WkT, bkF, tmat, qbws);
    // M8: scores -> softmax -> ctxE
    attn_kernel<<<dim3(B_), 256, 0, stream>>>(s, tmat, qbws, ctxE, i);
    // M9: ctxh[b, h*64+a] = ctxE[b,h,:] @ W_v[:, h*64+a] + b_v  (z = h)
    mm64<<<dim3(1, B_ / 64, NH_), 256, 0, stream>>>(
        ctxE, (long)NH_ * E_, E_, WvF, QK_, 64, bvF, 64, nullptr, 0,
        ctxh, QK_, 64, E_, 0);
    // M10: context = ctxh @ W_o + b_o
    mm64<<<dim3(E_ / 64, B_ / 64, 1), 256, 0, stream>>>(
        ctxh, QK_, 0, WoF, E_, 0, boF, 0, nullptr, 0, ctxv, E_, 0, QK_, 0);

    float* tmp = h_in; h_in = h_out; h_out = tmp;
  }
  // Output = s at step T-1 (same fold_in(key,127) noise as eps_last) — already in d_out.
}

// Round 3
// 27317.432 us; speedup vs baseline: 2.5339x; 2.5339x over previous
//
#include <hip/hip_runtime.h>

// Problem constants
#define B_   128
#define T_   128
#define E_   1024
#define H_   1024
#define A_   64
#define NH_  8
#define G_   3072
#define QK_  512
#define SCALE_ 0.125f

// ---------------------------------------------------------------------------
// JAX Threefry-2x32-20 (bit-exact) + XLA f32 erfinv path
// ---------------------------------------------------------------------------
__device__ __forceinline__ unsigned rotl32(unsigned x, int r) {
  return (x << r) | (x >> (32 - r));
}

__device__ __forceinline__ void tf2x32(unsigned k0, unsigned k1,
                                       unsigned x0, unsigned x1,
                                       unsigned& o0, unsigned& o1) {
  unsigned k2 = k0 ^ k1 ^ 0x1BD11BDAu;
  x0 += k0; x1 += k1;
  x0 += x1; x1 = rotl32(x1, 13); x1 ^= x0;
  x0 += x1; x1 = rotl32(x1, 15); x1 ^= x0;
  x0 += x1; x1 = rotl32(x1, 26); x1 ^= x0;
  x0 += x1; x1 = rotl32(x1,  6); x1 ^= x0;
  x0 += k1; x1 += k2 + 1u;
  x0 += x1; x1 = rotl32(x1, 17); x1 ^= x0;
  x0 += x1; x1 = rotl32(x1, 29); x1 ^= x0;
  x0 += x1; x1 = rotl32(x1, 16); x1 ^= x0;
  x0 += x1; x1 = rotl32(x1, 24); x1 ^= x0;
  x0 += k2; x1 += k0 + 2u;
  x0 += x1; x1 = rotl32(x1, 13); x1 ^= x0;
  x0 += x1; x1 = rotl32(x1, 15); x1 ^= x0;
  x0 += x1; x1 = rotl32(x1, 26); x1 ^= x0;
  x0 += x1; x1 = rotl32(x1,  6); x1 ^= x0;
  x0 += k0; x1 += k1 + 3u;
  x0 += x1; x1 = rotl32(x1, 17); x1 ^= x0;
  x0 += x1; x1 = rotl32(x1, 29); x1 ^= x0;
  x0 += x1; x1 = rotl32(x1, 16); x1 ^= x0;
  x0 += x1; x1 = rotl32(x1, 24); x1 ^= x0;
  x0 += k1; x1 += k2 + 4u;
  x0 += x1; x1 = rotl32(x1, 13); x1 ^= x0;
  x0 += x1; x1 = rotl32(x1, 15); x1 ^= x0;
  x0 += x1; x1 = rotl32(x1, 26); x1 ^= x0;
  x0 += x1; x1 = rotl32(x1,  6); x1 ^= x0;
  x0 += k2; x1 += k0 + 5u;
  o0 = x0; o1 = x1;
}

__device__ __forceinline__ float bits_to_normal(unsigned bits) {
  float uf = __uint_as_float((bits >> 9) | 0x3F800000u) - 1.0f;
  const float LO = -0.99999994f;
  float u = fmaxf(LO, uf * 2.0f + LO);
  float w = -log1pf(-u * u);
  float p;
  if (w < 5.0f) {
    w -= 2.5f;
    p = 2.81022636e-08f;
    p = fmaf(p, w, 3.43273939e-07f);
    p = fmaf(p, w, -3.5233877e-06f);
    p = fmaf(p, w, -4.39150654e-06f);
    p = fmaf(p, w, 0.00021858087f);
    p = fmaf(p, w, -0.00125372503f);
    p = fmaf(p, w, -0.00417768164f);
    p = fmaf(p, w, 0.246640727f);
    p = fmaf(p, w, 1.50140941f);
  } else {
    w = sqrtf(w) - 3.0f;
    p = -0.000200214257f;
    p = fmaf(p, w, 0.000100950558f);
    p = fmaf(p, w, 0.00134934322f);
    p = fmaf(p, w, -0.00367342844f);
    p = fmaf(p, w, 0.00573950773f);
    p = fmaf(p, w, -0.0076224613f);
    p = fmaf(p, w, 0.00943887047f);
    p = fmaf(p, w, 1.00167406f);
    p = fmaf(p, w, 2.83297682f);
  }
  return 1.41421356f * p * u;
}

__device__ __forceinline__ float sigmoidf_(float x) {
  return 1.0f / (1.0f + expf(-x));
}

__device__ __forceinline__ float ld_elem(const void* p, long i, int isb) {
  if (isb) {
    unsigned short u = ((const unsigned short*)p)[i];
    return __uint_as_float(((unsigned)u) << 16);
  }
  return ((const float*)p)[i];
}

// ---------------------------------------------------------------------------
// dtype sniffer + converter (unchanged from R2 — verified)
// ---------------------------------------------------------------------------
__global__ __launch_bounds__(256) void sniff_kernel(const void* encs, int* flag) {
  __shared__ int cnt;
  if (threadIdx.x == 0) cnt = 0;
  __syncthreads();
  const unsigned* w = (const unsigned*)encs;
  int c = 0;
  for (int i = threadIdx.x; i < 4096; i += 256) {
    unsigned e7 = (w[i] >> 8) & 0x7F;
    if (e7 >= 0x3B && e7 <= 0x41) c++;
  }
  atomicAdd(&cnt, c);
  __syncthreads();
  if (threadIdx.x == 0) flag[0] = (cnt > 2048) ? 1 : 0;
}

__global__ __launch_bounds__(256) void conv_kernel(const void* src, float* dst,
                                                   long n, const int* flag) {
  long i = (long)blockIdx.x * 256 + threadIdx.x;
  int isb = flag[0];
  if (i < n) dst[i] = ld_elem(src, i, isb);
}

// ---------------------------------------------------------------------------
// trans: build Wbig (2048x4096 interleaved-4), Wms (1024x2048), WkT (512x1024),
// Wenc4 (1024x4096), bias4, zero xh/h, skeys.  grid (16384, 5)
// ---------------------------------------------------------------------------
__global__ __launch_bounds__(256) void trans_kernel(
    const void* W_ih, const void* W_hh, const void* W_mu, const void* W_sig,
    const void* W_k, const float* __restrict__ bihF, const float* __restrict__ bhhF,
    float* __restrict__ Wbig, float* __restrict__ Wms, float* __restrict__ WkT,
    float* __restrict__ Wenc4, float* __restrict__ bias4,
    float* __restrict__ xh, float* __restrict__ h, unsigned* __restrict__ skeys,
    const int* flag)
{
  long idx = (long)blockIdx.x * 256 + threadIdx.x;
  int y = blockIdx.y;
  int isb = flag[0];
  if (y == 0) {                       // Wbig ctx rows (0..1023)
    if (idx < 4194304) {
      int e = (int)(idx & 1023); int col = (int)(idx >> 10);
      int j = col >> 2, c = col & 3;
      float v = 0.f;
      if (c < 3) v = ld_elem(W_ih, (long)(c * 1024 + j) * 2048 + 1024 + e, isb);
      Wbig[(long)e * 4096 + col] = v;
    }
  } else if (y == 1) {                // Wbig h rows (1024..2047)
    if (idx < 4194304) {
      int e = (int)(idx & 1023); int col = (int)(idx >> 10);
      int j = col >> 2, c = col & 3;
      float v = 0.f;
      if (c == 0)      v = ld_elem(W_hh, (long)j * 1024 + e, isb);
      else if (c == 1) v = ld_elem(W_hh, (long)(1024 + j) * 1024 + e, isb);
      else if (c == 3) v = ld_elem(W_hh, (long)(2048 + j) * 1024 + e, isb);
      Wbig[(long)(1024 + e) * 4096 + col] = v;
    }
  } else if (y == 2) {                // Wms
    if (idx < 2097152) {
      int k = (int)(idx >> 11), n = (int)(idx & 2047);
      float v = (n < 1024) ? ld_elem(W_mu, (long)k * 1024 + n, isb)
                           : ld_elem(W_sig, (long)k * 1024 + (n - 1024), isb);
      Wms[idx] = v;
    }
  } else if (y == 3) {                // WkT + bias4 + zero + skeys
    if (idx < 524288) {
      int qk = (int)(idx >> 10), e = (int)(idx & 1023);
      WkT[idx] = ld_elem(W_k, (long)e * 512 + qk, isb);
    }
    if (idx < 4096) {
      int j = (int)(idx >> 2), c = (int)(idx & 3);
      float v;
      if (c == 0)      v = bihF[j] + bhhF[j];
      else if (c == 1) v = bihF[1024 + j] + bhhF[1024 + j];
      else if (c == 2) v = bihF[2048 + j];
      else             v = bhhF[2048 + j];
      bias4[idx] = v;
    }
    if (idx < 262144) xh[idx] = 0.f;
    if (idx < 131072) h[idx] = 0.f;
    if (idx < 128) {
      unsigned o0, o1;
      tf2x32(0u, 1234u, 0u, (unsigned)idx, o0, o1);
      skeys[2 * idx] = o0; skeys[2 * idx + 1] = o1;
    }
  } else {                            // Wenc4
    if (idx < 4194304) {
      int e = (int)(idx & 1023); int col = (int)(idx >> 10);
      int j = col >> 2, c = col & 3;
      float v = 0.f;
      if (c < 3) v = ld_elem(W_ih, (long)(c * 1024 + j) * 2048 + e, isb);
      Wenc4[(long)e * 4096 + col] = v;
    }
  }
}

// ---------------------------------------------------------------------------
// consts: bqk[h][e], qbc[h], bvo[e].  grid (32)
// ---------------------------------------------------------------------------
__global__ __launch_bounds__(256) void consts_kernel(
    const float* __restrict__ bqF, const float* __restrict__ bkF,
    const float* __restrict__ bvF, const float* __restrict__ boF,
    const float* __restrict__ WkT, const float* __restrict__ WoF,
    float* __restrict__ bqk, float* __restrict__ qbc, float* __restrict__ bvo)
{
  int idx = blockIdx.x * 256 + threadIdx.x;  // < 8192
  int hh = idx >> 10, e = idx & 1023;
  float s = 0.f;
  for (int a = 0; a < 64; ++a)
    s += bqF[hh * 64 + a] * WkT[(long)(hh * 64 + a) * 1024 + e];
  bqk[idx] = s;
  if (idx < 1024) {
    float v = boF[idx];
    for (int ha = 0; ha < 512; ++ha) v += bvF[ha] * WoF[(long)ha * 1024 + idx];
    bvo[idx] = v;
  }
  if (idx < 8) {
    float v = 0.f;
    for (int a = 0; a < 64; ++a) v += bqF[idx * 64 + a] * bkF[idx * 64 + a];
    qbc[idx] = v;
  }
}

// ---------------------------------------------------------------------------
// mm128: 128x128 tile, 8x8/thread, split-K partial store.
// grid (N/128, M/128, heads*S); z -> head = z/S, split = z%S.
// A can be a sum of nsumA partials (stride psA).
// ---------------------------------------------------------------------------
__global__ __launch_bounds__(256) void mm128(
    const float* __restrict__ A, long lda, long zA, int nsumA, long psA,
    const float* __restrict__ Bm, long ldb, long zB,
    float* __restrict__ C, long ldc, long zC, long pstride,
    int Ktot, int S)
{
  int zz = blockIdx.z;
  int head = zz / S, sp = zz - head * S;
  int Kc = Ktot / S;
  long kb = (long)sp * Kc;
  A += (long)head * zA;
  Bm += (long)head * zB;
  C += (long)head * zC + (long)sp * pstride;
  long m0 = (long)blockIdx.y * 128;
  long n0 = (long)blockIdx.x * 128;
  __shared__ float As[16][132];
  __shared__ float Bs[16][132];
  int tid = threadIdx.x;
  int tx = tid & 15, ty = tid >> 4;
  int am = tid >> 2, ac = tid & 3;
  int bk = tid >> 5, bn = tid & 31;
  float acc[8][8];
  #pragma unroll
  for (int i = 0; i < 8; ++i)
    #pragma unroll
    for (int j = 0; j < 8; ++j) acc[i][j] = 0.f;

  for (int k0 = 0; k0 < Kc; k0 += 16) {
    const float* Ap0 = A + (m0 + am) * lda + kb + k0 + 4 * ac;
    const float* Ap1 = A + (m0 + am + 64) * lda + kb + k0 + 4 * ac;
    float4 a0 = *(const float4*)Ap0;
    float4 a1 = *(const float4*)Ap1;
    for (int s2 = 1; s2 < nsumA; ++s2) {
      float4 t0 = *(const float4*)(Ap0 + (long)s2 * psA);
      float4 t1 = *(const float4*)(Ap1 + (long)s2 * psA);
      a0.x += t0.x; a0.y += t0.y; a0.z += t0.z; a0.w += t0.w;
      a1.x += t1.x; a1.y += t1.y; a1.z += t1.z; a1.w += t1.w;
    }
    float4 b0 = *(const float4*)(Bm + (kb + k0 + bk) * ldb + n0 + 4 * bn);
    float4 b1 = *(const float4*)(Bm + (kb + k0 + bk + 8) * ldb + n0 + 4 * bn);
    __syncthreads();
    As[4 * ac + 0][am] = a0.x; As[4 * ac + 1][am] = a0.y;
    As[4 * ac + 2][am] = a0.z; As[4 * ac + 3][am] = a0.w;
    As[4 * ac + 0][am + 64] = a1.x; As[4 * ac + 1][am + 64] = a1.y;
    As[4 * ac + 2][am + 64] = a1.z; As[4 * ac + 3][am + 64] = a1.w;
    *(float4*)&Bs[bk][4 * bn] = b0;
    *(float4*)&Bs[bk + 8][4 * bn] = b1;
    __syncthreads();
    #pragma unroll
    for (int kk = 0; kk < 16; ++kk) {
      float4 av0 = *(const float4*)&As[kk][ty * 4];
      float4 av1 = *(const float4*)&As[kk][64 + ty * 4];
      float4 bv0 = *(const float4*)&Bs[kk][tx * 4];
      float4 bv1 = *(const float4*)&Bs[kk][64 + tx * 4];
      float amv[8] = {av0.x, av0.y, av0.z, av0.w, av1.x, av1.y, av1.z, av1.w};
      float bnv[8] = {bv0.x, bv0.y, bv0.z, bv0.w, bv1.x, bv1.y, bv1.z, bv1.w};
      #pragma unroll
      for (int i = 0; i < 8; ++i)
        #pragma unroll
        for (int j = 0; j < 8; ++j)
          acc[i][j] = fmaf(amv[i], bnv[j], acc[i][j]);
    }
  }

  #pragma unroll
  for (int i = 0; i < 8; ++i) {
    long r = m0 + (long)(i >> 2) * 64 + ty * 4 + (i & 3);
    float4 v0 = {acc[i][0], acc[i][1], acc[i][2], acc[i][3]};
    float4 v1 = {acc[i][4], acc[i][5], acc[i][6], acc[i][7]};
    *(float4*)(C + r * ldc + n0 + tx * 4) = v0;
    *(float4*)(C + r * ldc + n0 + 64 + tx * 4) = v1;
  }
}

// ---------------------------------------------------------------------------
// mm64s: 64x64 tile, 4x4/thread, split-K partial store (for narrow-N V GEMM)
// ---------------------------------------------------------------------------
__global__ __launch_bounds__(256) void mm64s(
    const float* __restrict__ A, long lda, long zA,
    const float* __restrict__ Bm, long ldb, long zB,
    float* __restrict__ C, long ldc, long zC, long pstride,
    int Ktot, int S)
{
  int zz = blockIdx.z;
  int head = zz / S, sp = zz - head * S;
  int Kc = Ktot / S;
  long kb = (long)sp * Kc;
  A += (long)head * zA; Bm += (long)head * zB;
  C += (long)head * zC + (long)sp * pstride;
  long n0 = (long)blockIdx.x * 64;
  long m0 = (long)blockIdx.y * 64;
  __shared__ float As[16][68];
  __shared__ float Bs[16][68];
  int tid = threadIdx.x;
  int tx = tid & 15, ty = tid >> 4;
  int ar = tid >> 2, ac = tid & 3;
  int br = tid >> 4, bc = tid & 15;
  float acc[4][4];
  #pragma unroll
  for (int i = 0; i < 4; ++i)
    #pragma unroll
    for (int j = 0; j < 4; ++j) acc[i][j] = 0.f;

  for (int k0 = 0; k0 < Kc; k0 += 16) {
    float4 a4 = *(const float4*)(A + (m0 + ar) * lda + kb + k0 + 4 * ac);
    float4 b4 = *(const float4*)(Bm + (kb + k0 + br) * ldb + n0 + 4 * bc);
    __syncthreads();
    As[4 * ac + 0][ar] = a4.x; As[4 * ac + 1][ar] = a4.y;
    As[4 * ac + 2][ar] = a4.z; As[4 * ac + 3][ar] = a4.w;
    *(float4*)(&Bs[br][4 * bc]) = b4;
    __syncthreads();
    #pragma unroll
    for (int kk = 0; kk < 16; ++kk) {
      float4 av = *(const float4*)(&As[kk][4 * ty]);
      float4 bv = *(const float4*)(&Bs[kk][4 * tx]);
      float amv[4] = {av.x, av.y, av.z, av.w};
      float bnv[4] = {bv.x, bv.y, bv.z, bv.w};
      #pragma unroll
      for (int im = 0; im < 4; ++im)
        #pragma unroll
        for (int jn = 0; jn < 4; ++jn)
          acc[im][jn] = fmaf(amv[im], bnv[jn], acc[im][jn]);
    }
  }
  #pragma unroll
  for (int im = 0; im < 4; ++im) {
    long m = m0 + ty * 4 + im;
    float4 v = {acc[im][0], acc[im][1], acc[im][2], acc[im][3]};
    *(float4*)(C + m * ldc + n0 + tx * 4) = v;
  }
}

// ---------------------------------------------------------------------------
// GRU epilogue: sum 8 partials (interleaved r,z,inn,hn) + gie4 + bias4 -> h
// ---------------------------------------------------------------------------
__global__ __launch_bounds__(256) void gru_epi(
    const float* __restrict__ gsumP, const float* __restrict__ gie4,
    const float* __restrict__ bias4, float* __restrict__ h,
    float* __restrict__ xh)
{
  int idx = blockIdx.x * 256 + threadIdx.x;  // < B*H
  int b = idx >> 10, j = idx & 1023;
  float4 v = ((const float4*)gie4)[(long)b * 1024 + j];
  float4 bb = ((const float4*)bias4)[j];
  v.x += bb.x; v.y += bb.y; v.z += bb.z; v.w += bb.w;
  #pragma unroll
  for (int s = 0; s < 8; ++s) {
    float4 t = ((const float4*)gsumP)[(long)s * 131072 + (long)b * 1024 + j];
    v.x += t.x; v.y += t.y; v.z += t.z; v.w += t.w;
  }
  float r = sigmoidf_(v.x);
  float z = sigmoidf_(v.y);
  float n = tanhf(v.z + r * v.w);
  float ho = h[idx];
  float hn = (1.0f - z) * n + z * ho;
  h[idx] = hn;
  xh[(long)b * 2048 + 1024 + j] = hn;
}

// ---------------------------------------------------------------------------
// mu/sig epilogue: sum 8 partials + bias (+softplus for sig cols)
// ---------------------------------------------------------------------------
__global__ __launch_bounds__(256) void musig_epi(
    const float* __restrict__ msP, const float* __restrict__ bmuF,
    const float* __restrict__ bsigF, float* __restrict__ mus,
    float* __restrict__ sigs, int step)
{
  int idx = blockIdx.x * 256 + threadIdx.x;  // < B*2048
  int b = idx >> 11, n = idx & 2047;
  float v = 0.f;
  #pragma unroll
  for (int s = 0; s < 8; ++s) v += msP[(long)s * 262144 + idx];
  if (n < 1024) {
    mus[((long)b * T_ + step) * E_ + n] = v + bmuF[n];
  } else {
    float x = v + bsigF[n - 1024];
    sigs[((long)b * T_ + step) * E_ + (n - 1024)] =
        fmaxf(x, 0.0f) + log1pf(expf(-fabsf(x)));
  }
}

// ---------------------------------------------------------------------------
// gen_s: s = mus + N(0,1)*sigs, 4 elements/thread.  grid (step+1, 128)
// ---------------------------------------------------------------------------
__global__ __launch_bounds__(256) void gen_s(
    const float* __restrict__ mus, const float* __restrict__ sigs,
    float* __restrict__ s, const unsigned* __restrict__ skeys, int step)
{
  int t = blockIdx.x;
  int b = blockIdx.y;
  int e = threadIdx.x * 4;
  unsigned sk0 = skeys[2 * step], sk1 = skeys[2 * step + 1];
  unsigned f = (unsigned)(b * (T_ * E_) + t * E_ + e);
  unsigned o0, o1;
  float nv[4];
  tf2x32(sk0, sk1, 0u, f + 0u, o0, o1); nv[0] = bits_to_normal(o0 ^ o1);
  tf2x32(sk0, sk1, 0u, f + 1u, o0, o1); nv[1] = bits_to_normal(o0 ^ o1);
  tf2x32(sk0, sk1, 0u, f + 2u, o0, o1); nv[2] = bits_to_normal(o0 ^ o1);
  tf2x32(sk0, sk1, 0u, f + 3u, o0, o1); nv[3] = bits_to_normal(o0 ^ o1);
  long i4 = (((long)b * T_ + t) * E_ + e) >> 2;
  float4 mu = ((const float4*)mus)[i4];
  float4 sg = ((const float4*)sigs)[i4];
  float4 out;
  out.x = fmaf(nv[0], sg.x, mu.x);
  out.y = fmaf(nv[1], sg.y, mu.y);
  out.z = fmaf(nv[2], sg.z, mu.z);
  out.w = fmaf(nv[3], sg.w, mu.w);
  ((float4*)s)[i4] = out;
}

// ---------------------------------------------------------------------------
// t_kernel: t[b,h,e] = sum_a q[b,ha]*WkT[ha,e] + bqk; qb = q.bk + qbc
// q summed from 8 partials.  grid (4, 8, 16)
// ---------------------------------------------------------------------------
__global__ __launch_bounds__(256) void t_kernel(
    const float* __restrict__ qP, const float* __restrict__ WkT,
    const float* __restrict__ bkF, const float* __restrict__ bqk,
    const float* __restrict__ qbc, float* __restrict__ tmat,
    float* __restrict__ qb)
{
  int e = blockIdx.x * 256 + threadIdx.x;
  int hh = blockIdx.y;
  int b0 = blockIdx.z * 8;
  __shared__ float q_l[8][64];
  int tid = threadIdx.x;
  for (int idx2 = tid; idx2 < 512; idx2 += 256) {
    int bb = idx2 >> 6, a = idx2 & 63;
    float v = 0.f;
    #pragma unroll
    for (int s = 0; s < 8; ++s)
      v += qP[(long)s * 65536 + (long)(b0 + bb) * 512 + hh * 64 + a];
    q_l[bb][a] = v;
  }
  __syncthreads();
  float acc[8];
  #pragma unroll
  for (int bb = 0; bb < 8; ++bb) acc[bb] = 0.f;
  for (int a = 0; a < 64; ++a) {
    float wv = WkT[(long)(hh * 64 + a) * 1024 + e];
    #pragma unroll
    for (int bb = 0; bb < 8; ++bb) acc[bb] = fmaf(q_l[bb][a], wv, acc[bb]);
  }
  float bq_ = bqk[hh * 1024 + e];
  #pragma unroll
  for (int bb = 0; bb < 8; ++bb)
    tmat[((long)(b0 + bb) * NH_ + hh) * 1024 + e] = acc[bb] + bq_;
  if (blockIdx.x == 0 && tid < 8) {
    int bb = tid;
    float sm = qbc[hh];
    for (int a = 0; a < 64; ++a) sm += q_l[bb][a] * bkF[hh * 64 + a];
    qb[(b0 + bb) * NH_ + hh] = sm;
  }
}

// ---------------------------------------------------------------------------
// scores: sc[b,h,j] = SCALE*(sum_e s[b,j,e]*t[b,h,e] + qb).  grid (jt, 128)
// ---------------------------------------------------------------------------
__global__ __launch_bounds__(256) void scores_kernel(
    const float* __restrict__ s, const float* __restrict__ tmat,
    const float* __restrict__ qb, float* __restrict__ scg, int step)
{
  int b = blockIdx.y;
  int jbase = blockIdx.x * 32;
  __shared__ float s_ch[32][132];
  __shared__ float t_ch[8][132];
  int tid = threadIdx.x;
  int hh = tid >> 5, jj = tid & 31;
  int j = jbase + jj;
  float acc = 0.f;
  for (int e0 = 0; e0 < 1024; e0 += 128) {
    __syncthreads();
    #pragma unroll
    for (int q = 0; q < 4; ++q) {
      int f = tid + q * 256;
      int jr = f >> 5, e4 = f & 31;
      int jg = jbase + jr;
      if (jg <= step)
        *(float4*)&s_ch[jr][e4 * 4] =
            *(const float4*)&s[((long)b * T_ + jg) * E_ + e0 + e4 * 4];
    }
    {
      int e4 = tid & 31, h2 = tid >> 5;
      *(float4*)&t_ch[h2][e4 * 4] =
          *(const float4*)&tmat[((long)b * NH_ + h2) * E_ + e0 + e4 * 4];
    }
    __syncthreads();
    if (j <= step) {
      #pragma unroll
      for (int e4 = 0; e4 < 32; ++e4) {
        float4 sv = *(const float4*)&s_ch[jj][e4 * 4];
        float4 tv = *(const float4*)&t_ch[hh][e4 * 4];
        acc = fmaf(sv.x, tv.x, acc);
        acc = fmaf(sv.y, tv.y, acc);
        acc = fmaf(sv.z, tv.z, acc);
        acc = fmaf(sv.w, tv.w, acc);
      }
    }
  }
  if (j <= step)
    scg[((long)b * NH_ + hh) * T_ + j] = (acc + qb[b * NH_ + hh]) * SCALE_;
}

// ---------------------------------------------------------------------------
// ctxE: inline softmax + weighted sum of s.  grid (16, 128)
// ---------------------------------------------------------------------------
__global__ __launch_bounds__(256) void ctx_kernel(
    const float* __restrict__ s, const float* __restrict__ scg,
    float* __restrict__ ctxE, int step)
{
  int b = blockIdx.y;
  int et = blockIdx.x;
  __shared__ float w_l[NH_][T_];
  __shared__ float s_l[32][68];
  int tid = threadIdx.x;
  {
    int hh = tid >> 5, l = tid & 31;
    const float* sc = scg + ((long)b * NH_ + hh) * T_;
    float m = -3.0e38f;
    for (int j = l; j <= step; j += 32) m = fmaxf(m, sc[j]);
    for (int off = 16; off; off >>= 1) m = fmaxf(m, __shfl_xor(m, off, 32));
    float d = 0.f;
    for (int j = l; j <= step; j += 32) {
      float pe = expf(sc[j] - m);
      w_l[hh][j] = pe;
      d += pe;
    }
    for (int off = 16; off; off >>= 1) d += __shfl_xor(d, off, 32);
    float inv = 1.0f / d;
    for (int j = l; j <= step; j += 32) w_l[hh][j] *= inv;
  }
  int e = tid & 63, hp = tid >> 6;  // hp 0..3, h in {hp, hp+4}
  float acc0 = 0.f, acc1 = 0.f;
  for (int jc = 0; jc <= step; jc += 32) {
    __syncthreads();
    #pragma unroll
    for (int q = 0; q < 8; ++q) {
      int f = tid + q * 256;
      int jr = f >> 6, ee = f & 63;
      int jg = jc + jr;
      if (jg <= step)
        s_l[jr][ee] = s[((long)b * T_ + jg) * E_ + et * 64 + ee];
    }
    __syncthreads();
    int jmax = min(31, step - jc);
    for (int jr = 0; jr <= jmax; ++jr) {
      float sv = s_l[jr][e];
      acc0 = fmaf(w_l[hp][jc + jr], sv, acc0);
      acc1 = fmaf(w_l[hp + 4][jc + jr], sv, acc1);
    }
  }
  ctxE[((long)b * NH_ + hp) * E_ + et * 64 + e] = acc0;
  ctxE[((long)b * NH_ + hp + 4) * E_ + et * 64 + e] = acc1;
}

// ---------------------------------------------------------------------------
// finalize: xh[:, :1024] = sum ctxvP + bvo.  grid (128)
// ---------------------------------------------------------------------------
__global__ __launch_bounds__(256) void fin_kernel(
    const float* __restrict__ ctxvP, const float* __restrict__ bvo,
    float* __restrict__ xh)
{
  int i4 = blockIdx.x * 256 + threadIdx.x;  // < 32768 float4s
  int b = i4 >> 8, e4 = i4 & 255;
  float4 v = ((const float4*)bvo)[e4];
  #pragma unroll
  for (int s = 0; s < 4; ++s) {
    float4 t = ((const float4*)ctxvP)[(long)s * 32768 + (long)b * 256 + e4];
    v.x += t.x; v.y += t.y; v.z += t.z; v.w += t.w;
  }
  ((float4*)xh)[(long)b * 512 + e4] = v;
}

// ---------------------------------------------------------------------------
// Host side
// ---------------------------------------------------------------------------
extern "C" void kernel_launch(void* const* d_in, const int* in_sizes, int n_in,
                              void* d_out, int out_size, void* d_ws, size_t ws_size,
                              hipStream_t stream) {
  (void)in_sizes; (void)n_in; (void)out_size; (void)ws_size;
  const void* encs  = d_in[0];
  const void* W_ih  = d_in[1];
  const void* W_hh  = d_in[2];
  const void* b_ih  = d_in[3];
  const void* b_hh  = d_in[4];
  const void* W_mu  = d_in[5];
  const void* b_mu  = d_in[6];
  const void* W_sig = d_in[7];
  const void* b_sig = d_in[8];
  const void* W_q   = d_in[9];
  const void* b_q   = d_in[10];
  const void* W_k   = d_in[11];
  const void* b_k   = d_in[12];
  const void* W_v   = d_in[13];
  const void* b_v   = d_in[14];
  const void* W_o   = d_in[15];
  const void* b_o   = d_in[16];

  float* s = (float*)d_out;
  float* w = (float*)d_ws;

  int*   flag   = (int*)w;
  float* p      = w + 1024;
  float* WbigF  = p;  p += (size_t)2048 * 4096;   // 8.39M
  float* WmsF   = p;  p += (size_t)1024 * 2048;   // 2.10M
  float* WkTF   = p;  p += (size_t)512 * 1024;
  float* WqF    = p;  p += (size_t)1024 * 512;
  float* WvF    = p;  p += (size_t)1024 * 512;
  float* WoF    = p;  p += (size_t)512 * 1024;
  float* encsF  = p;  p += (size_t)B_ * E_;
  float* bihF   = p;  p += 4096;
  float* bhhF   = p;  p += 4096;
  float* bmuF   = p;  p += 1024;
  float* bsigF  = p;  p += 1024;
  float* bqF    = p;  p += 1024;
  float* bkF    = p;  p += 1024;
  float* bvF    = p;  p += 1024;
  float* boF    = p;  p += 1024;
  float* bias4  = p;  p += 4096;
  float* bqk    = p;  p += 8192;
  float* qbc    = p;  p += 1024;
  float* bvo    = p;  p += 1024;
  unsigned* skeys = (unsigned*)p; p += 1024;
  float* gie4   = p;  p += (size_t)B_ * 4096;     // 0.52M
  float* xh     = p;  p += (size_t)B_ * 2048;     // [ctx | h]
  float* hbuf   = p;  p += (size_t)B_ * 1024;
  float* gsumP  = p;  p += (size_t)8 * B_ * 4096; // 4.19M (aliased as Wenc4 in prep)
  float* musigP = p;  p += (size_t)8 * B_ * 2048; // 2.10M
  float* qP     = p;  p += (size_t)8 * B_ * 512;  // 0.52M
  float* tmat   = p;  p += (size_t)B_ * NH_ * E_; // 1.05M
  float* qbv    = p;  p += 1024;
  float* scg    = p;  p += (size_t)B_ * NH_ * T_; // 0.13M
  float* ctxE   = p;  p += (size_t)B_ * NH_ * E_; // 1.05M
  float* ctxhP  = p;  p += (size_t)4 * B_ * 512;  // 0.26M
  float* ctxvP  = p;  p += (size_t)4 * B_ * 1024; // 0.52M
  float* mus    = p;  p += (size_t)B_ * T_ * E_;  // 16.8M
  float* sigs   = p;  p += (size_t)B_ * T_ * E_;  // 16.8M
  float* Wenc4  = gsumP;  // prep-only alias (consumed before first G1 write)

  // ---- prep ----
  sniff_kernel<<<1, 256, 0, stream>>>(encs, flag);
  auto conv = [&](const void* src, float* dst, long n) {
    conv_kernel<<<dim3((unsigned)((n + 255) / 256)), 256, 0, stream>>>(src, dst, n, flag);
  };
  conv(encs,  encsF, (long)B_ * E_);
  conv(b_ih,  bihF,  G_);
  conv(b_hh,  bhhF,  G_);
  conv(b_mu,  bmuF,  1024);
  conv(b_sig, bsigF, 1024);
  conv(b_q,   bqF,   512);
  conv(b_k,   bkF,   512);
  conv(b_v,   bvF,   512);
  conv(b_o,   boF,   1024);
  conv(W_q,   WqF,   (long)1024 * 512);
  conv(W_v,   WvF,   (long)1024 * 512);
  conv(W_o,   WoF,   (long)512 * 1024);

  trans_kernel<<<dim3(16384, 5), 256, 0, stream>>>(
      W_ih, W_hh, W_mu, W_sig, W_k, bihF, bhhF,
      WbigF, WmsF, WkTF, Wenc4, bias4, xh, hbuf, skeys, flag);
  consts_kernel<<<dim3(32), 256, 0, stream>>>(
      bqF, bkF, bvF, boF, WkTF, WoF, bqk, qbc, bvo);
  // gie4 = encs @ Wenc4  (reads the gsumP-aliased Wenc4 BEFORE the loop)
  mm128<<<dim3(32, 1, 1), 256, 0, stream>>>(
      encsF, 1024, 0, 1, 0, Wenc4, 4096, 0, gie4, 4096, 0, 0, 1024, 1);

  // ---- 128-step scan ----
  for (int i = 0; i < T_; ++i) {
    // G1: gsumP = xh @ Wbig  (interleaved r,z,inn,hn), split-8
    mm128<<<dim3(32, 1, 8), 256, 0, stream>>>(
        xh, 2048, 0, 1, 0, WbigF, 4096, 0, gsumP, 4096, 0, 524288, 2048, 8);
    gru_epi<<<dim3(512), 256, 0, stream>>>(gsumP, gie4, bias4, hbuf, xh);
    // G2: musigP = h @ [Wmu|Wsig], split-8
    mm128<<<dim3(16, 1, 8), 256, 0, stream>>>(
        hbuf, 1024, 0, 1, 0, WmsF, 2048, 0, musigP, 2048, 0, 262144, 1024, 8);
    musig_epi<<<dim3(1024), 256, 0, stream>>>(musigP, bmuF, bsigF, mus, sigs, i);
    // gen_s: rows 0..i
    gen_s<<<dim3(i + 1, B_), 256, 0, stream>>>(mus, sigs, s, skeys, i);
    // Q: qP = s_i @ Wq, split-8
    mm128<<<dim3(4, 1, 8), 256, 0, stream>>>(
        s + (long)i * E_, (long)T_ * E_, 0, 1, 0, WqF, 512, 0,
        qP, 512, 0, 65536, 1024, 8);
    t_kernel<<<dim3(4, 8, 16), 256, 0, stream>>>(
        qP, WkTF, bkF, bqk, qbc, tmat, qbv);
    scores_kernel<<<dim3((i + 32) / 32, B_), 256, 0, stream>>>(
        s, tmat, qbv, scg, i);
    ctx_kernel<<<dim3(16, B_), 256, 0, stream>>>(s, scg, ctxE, i);
    // V: ctxhP[s][b][h*64+a], per-head K=1024 split-4
    mm64s<<<dim3(1, 2, 32), 256, 0, stream>>>(
        ctxE, 8192, 1024, WvF, 512, 64, ctxhP, 512, 64, 65536, 1024, 4);
    // O: ctxvP = (sum ctxhP) @ Wo, split-4
    mm128<<<dim3(8, 1, 4), 256, 0, stream>>>(
        ctxhP, 512, 0, 4, 65536, WoF, 1024, 0, ctxvP, 1024, 0, 131072, 512, 4);
    fin_kernel<<<dim3(128), 256, 0, stream>>>(ctxvP, bvo, xh);
  }
  // d_out == s already holds step-127 sample (same fold_in(key,127) as eps_last)
}